// Round 1
// baseline (570.560 us; speedup 1.0000x reference)
//
#include <hip/hip_runtime.h>
#include <hip/hip_bf16.h>
#include <math.h>

typedef unsigned short u16;
typedef __attribute__((ext_vector_type(4))) unsigned short u16x4;
typedef __attribute__((ext_vector_type(8))) unsigned short u16x8;
typedef __attribute__((ext_vector_type(8))) short s16x8;
typedef __attribute__((ext_vector_type(4))) float f32x4;

#define B_  4
#define S_  2048
#define D_  2048
#define DI_ 1024
#define MROWS (B_ * S_)          // 8192
#define KDIM  D_                 // 2048
#define NDIM  D_                 // 2048
#define STRIP 16                 // rows per conv strip (divides S_)
#define NT    (KDIM / 32)        // 64 K-tiles

__device__ __forceinline__ float b2f(u16 u) {
    union { unsigned i; float f; } v; v.i = ((unsigned)u) << 16; return v.f;
}
__device__ __forceinline__ u16 f2b(float f) {
    unsigned u = __float_as_uint(f);
    unsigned r = (u + 0x7FFFu + ((u >> 16) & 1u)) >> 16;
    return (u16)r;
}
__device__ __forceinline__ float gelu_exact(float x) {
    return 0.5f * x * (1.0f + erff(x * 0.70710678118654752f));
}

#define GLOAD_LDS16(gp, lp)                                                    \
    __builtin_amdgcn_global_load_lds(                                          \
        (const __attribute__((address_space(1))) void*)(gp),                   \
        (__attribute__((address_space(3))) void*)(lp), 16, 0, 0)

// ---------------------------------------------------------------------------
// Transpose n x n, fp32 in -> bf16 out. DUAL=true: blockIdx.z picks src/dst.
// ---------------------------------------------------------------------------
__global__ void transpose_k(const float* __restrict__ in0, u16* __restrict__ out0,
                            const float* __restrict__ in1, u16* __restrict__ out1,
                            int n) {
    __shared__ float tile[32][33];
    const float* in = (blockIdx.z == 0) ? in0 : in1;
    u16* out = (blockIdx.z == 0) ? out0 : out1;
    int bx = blockIdx.x * 32, by = blockIdx.y * 32;
    int tx = threadIdx.x, ty = threadIdx.y;
    for (int i = 0; i < 32; i += 8)
        tile[ty + i][tx] = in[(size_t)(by + ty + i) * n + bx + tx];
    __syncthreads();
    for (int i = 0; i < 32; i += 8)
        out[(size_t)(bx + ty + i) * n + by + tx] = f2b(tile[tx][ty + i]);
}

// ---------------------------------------------------------------------------
// Short conv, strip-mined (fp32 in, bf16 out):
// grid (2, MROWS/STRIP); thread owns cols c..c+3 for STRIP consecutive rows,
// carrying taps m1/m2 in registers. Also zeroes wacc and t_g.
// ---------------------------------------------------------------------------
__global__ void shortconv_k(const float* __restrict__ x, const float* __restrict__ sw,
                            const float* __restrict__ sb, u16* __restrict__ xs,
                            float* __restrict__ wacc, float* __restrict__ t_g) {
    const int bid = blockIdx.y * 2 + blockIdx.x;
    {
        int z = bid * 256 + threadIdx.x;
        if (z < 12) wacc[z] = 0.0f;
        if (z < MROWS * 6) t_g[z] = 0.0f;
    }
    const int c = blockIdx.x * 1024 + threadIdx.x * 4;
    const int r0 = blockIdx.y * STRIP;
    const int t0 = r0 & (S_ - 1);

    float tap[12];
    #pragma unroll
    for (int q = 0; q < 3; ++q)
        ((f32x4*)tap)[q] = *(const f32x4*)(sw + (size_t)c * 3 + q * 4);
    f32x4 sbv = *(const f32x4*)(sb + c);

    const float* base = x + (size_t)r0 * D_ + c;
    f32x4 m2, m1;
    if (t0 == 0) { m2 = (f32x4)(0.0f); m1 = (f32x4)(0.0f); }
    else { m2 = *(const f32x4*)(base - 2 * D_); m1 = *(const f32x4*)(base - D_); }

    u16* op = xs + (size_t)r0 * D_ + c;
    #pragma unroll
    for (int rr = 0; rr < STRIP; ++rr) {
        f32x4 cur = *(const f32x4*)(base + (size_t)rr * D_);
        u16x4 outv;
        #pragma unroll
        for (int e = 0; e < 4; ++e) {
            float v = cur[e] + sbv[e]
                    + tap[e * 3 + 0] * m2[e]
                    + tap[e * 3 + 1] * m1[e]
                    + tap[e * 3 + 2] * cur[e];
            outv[e] = f2b(v);
        }
        *(u16x4*)(op + (size_t)rr * D_) = outv;
        m2 = m1; m1 = cur;
    }
}

// ---------------------------------------------------------------------------
// GEMM: 256x256 tile, BK=32, 8 waves (2x4), per-wave 128x64 output.
// 4-deep LDS K-tile ring (128 KiB), counted-vmcnt phase pipeline:
// per K-tile 2 phases of {ds_read || global_load_lds -> s_barrier ->
// lgkmcnt(0) -> setprio(1) 16xMFMA setprio(0) -> s_barrier}; one
// s_waitcnt vmcnt(8) per K-tile (never 0 in main loop).
// Staging: linear LDS dest + pre-swizzled global source; reads swizzled
// (chunk ^ ((row>>1)&3)) -> conflict-free (measured 0 at this pattern).
// FILT=true (GEMM1): epilogue folds gelu(acc+bias)*fw into t_g partials.
// FILT=false (GEMM2): C fp32 = acc + bias.
// ---------------------------------------------------------------------------
template <bool FILT>
__global__ __launch_bounds__(512, 2)
void gemm_k(const u16* __restrict__ A, const u16* __restrict__ BT,
            const float* __restrict__ bias, float* __restrict__ C,
            const float* __restrict__ fw, float* __restrict__ t_g,
            int M, int N, int K) {
    __shared__ u16 As[4][8192];   // 4 bufs x 256 rows x 32 k (64 KiB)
    __shared__ u16 Bs[4][8192];   // 4 bufs x 256 cols x 32 k (64 KiB)

    const int tid  = threadIdx.x;          // 0..511
    const int wid  = tid >> 6;             // 0..7
    const int lane = tid & 63;
    const int wr   = wid >> 2;             // 0..1 : row half (128 rows)
    const int wc   = wid & 3;              // 0..3 : col quarter (64 cols)
    const int row0 = blockIdx.y << 8;
    const int col0 = blockIdx.x << 8;

    // --- staging geometry: thread covers linear slot p = q*512 + tid ---
    const int rowS    = tid >> 2;                                   // 0..127
    const int colOffS = (((tid & 3) ^ ((rowS >> 1) & 3)) << 3);     // elem
    const u16* gA0 = A  + (size_t)(row0 + rowS) * KDIM + colOffS;
    const u16* gB0 = BT + (size_t)(col0 + rowS) * KDIM + colOffS;
    const int ldsOff0 = wid * 512;          // u16 units, q=0 wave base
    const int ldsOff1 = 4096 + wid * 512;   // q=1 wave base

#define STAGE_A(bufi, Tt) do {                                                 \
    const u16* _g = gA0 + (size_t)(Tt) * 32;                                   \
    GLOAD_LDS16(_g, &As[bufi][ldsOff0]);                                       \
    GLOAD_LDS16(_g + (size_t)128 * KDIM, &As[bufi][ldsOff1]);                  \
} while (0)
#define STAGE_B(bufi, Tt) do {                                                 \
    const u16* _g = gB0 + (size_t)(Tt) * 32;                                   \
    GLOAD_LDS16(_g, &Bs[bufi][ldsOff0]);                                       \
    GLOAD_LDS16(_g + (size_t)128 * KDIM, &Bs[bufi][ldsOff1]);                  \
} while (0)

    // --- fragment read offsets (u16 units), swizzled chunk ---
    int aoff[8], boff[4];
    #pragma unroll
    for (int i = 0; i < 8; ++i) {
        int row  = (wr << 7) + (i << 4) + (lane & 15);
        int slot = (lane >> 4) ^ ((row >> 1) & 3);
        aoff[i] = row * 32 + slot * 8;
    }
    #pragma unroll
    for (int j = 0; j < 4; ++j) {
        int row  = (wc << 6) + (j << 4) + (lane & 15);
        int slot = (lane >> 4) ^ ((row >> 1) & 3);
        boff[j] = row * 32 + slot * 8;
    }

    f32x4 acc[8][4];
    #pragma unroll
    for (int i = 0; i < 8; ++i)
        #pragma unroll
        for (int j = 0; j < 4; ++j) acc[i][j] = (f32x4)(0.0f);

#define PHASE_SYNC()                                                           \
    __builtin_amdgcn_sched_barrier(0);                                         \
    __builtin_amdgcn_s_barrier();                                              \
    asm volatile("s_waitcnt lgkmcnt(0)" ::: "memory");                         \
    __builtin_amdgcn_sched_barrier(0);

#define TILE_BODY(TT, STG, VMSTR) do {                                         \
    const int buf_ = (TT) & 3;                                                 \
    const int sb_  = ((TT) + 3) & 3;                                           \
    s16x8 af_[4], bf_[4];                                                      \
    _Pragma("unroll")                                                          \
    for (int j = 0; j < 4; ++j) bf_[j] = *(const s16x8*)&Bs[buf_][boff[j]];    \
    _Pragma("unroll")                                                          \
    for (int i = 0; i < 4; ++i) af_[i] = *(const s16x8*)&As[buf_][aoff[i]];    \
    if (STG) { STAGE_A(sb_, (TT) + 3); }                                       \
    PHASE_SYNC();                                                              \
    __builtin_amdgcn_s_setprio(1);                                             \
    _Pragma("unroll")                                                          \
    for (int i = 0; i < 4; ++i)                                                \
        _Pragma("unroll")                                                      \
        for (int j = 0; j < 4; ++j)                                            \
            acc[i][j] = __builtin_amdgcn_mfma_f32_16x16x32_bf16(               \
                af_[i], bf_[j], acc[i][j], 0, 0, 0);                           \
    __builtin_amdgcn_s_setprio(0);                                             \
    __builtin_amdgcn_sched_barrier(0);                                         \
    __builtin_amdgcn_s_barrier();                                              \
    _Pragma("unroll")                                                          \
    for (int i = 0; i < 4; ++i) af_[i] = *(const s16x8*)&As[buf_][aoff[i + 4]];\
    if (STG) { STAGE_B(sb_, (TT) + 3); }                                       \
    PHASE_SYNC();                                                              \
    __builtin_amdgcn_s_setprio(1);                                             \
    _Pragma("unroll")                                                          \
    for (int i = 0; i < 4; ++i)                                                \
        _Pragma("unroll")                                                      \
        for (int j = 0; j < 4; ++j)                                            \
            acc[i + 4][j] = __builtin_amdgcn_mfma_f32_16x16x32_bf16(           \
                af_[i], bf_[j], acc[i + 4][j], 0, 0, 0);                       \
    __builtin_amdgcn_s_setprio(0);                                             \
    __builtin_amdgcn_sched_barrier(0);                                         \
    asm volatile("s_waitcnt " VMSTR ::: "memory");                             \
    __builtin_amdgcn_s_barrier();                                              \
} while (0)

    // --- prologue: stage tiles 0,1,2 (tile-major so oldest 4 = tile 0) ---
    STAGE_A(0, 0); STAGE_B(0, 0);
    STAGE_A(1, 1); STAGE_B(1, 1);
    STAGE_A(2, 2); STAGE_B(2, 2);
    asm volatile("s_waitcnt vmcnt(8)" ::: "memory");
    __builtin_amdgcn_sched_barrier(0);
    __builtin_amdgcn_s_barrier();

    // --- main loop: stage T+3, counted vmcnt(8) per tile ---
    #pragma unroll 1
    for (int T = 0; T <= NT - 4; ++T) {
        TILE_BODY(T, true, "vmcnt(8)");
    }
    // --- epilogue tiles: no staging, drain ---
    TILE_BODY(NT - 3, false, "vmcnt(0)");
    TILE_BODY(NT - 2, false, "vmcnt(0)");
    TILE_BODY(NT - 1, false, "vmcnt(0)");

    // C/D layout: row = wr*128 + (lane>>4)*4 + i*16 + r, col = wc*64 + (lane&15) + j*16
    const int colt0 = (wc << 6) + (lane & 15);
    if (FILT) {
        float* t_lds = (float*)&As[0][0];
        __syncthreads();
        for (int z = tid; z < 768; z += 512) t_lds[z] = 0.0f;
        __syncthreads();
        float fwv[4][3], bsv[4];
        const int ibase = (col0 & (DI_ - 1)) + colt0;
        #pragma unroll
        for (int j = 0; j < 4; ++j) {
            int ifilt = ibase + j * 16;
            fwv[j][0] = fw[ifilt * 3 + 0];
            fwv[j][1] = fw[ifilt * 3 + 1];
            fwv[j][2] = fw[ifilt * 3 + 2];
            bsv[j] = bias[col0 + colt0 + j * 16];
        }
        #pragma unroll
        for (int i = 0; i < 8; ++i) {
            #pragma unroll
            for (int r = 0; r < 4; ++r) {
                float s0 = 0.f, s1 = 0.f, s2 = 0.f;
                #pragma unroll
                for (int j = 0; j < 4; ++j) {
                    float hv = gelu_exact(acc[i][j][r] + bsv[j]);
                    s0 += hv * fwv[j][0];
                    s1 += hv * fwv[j][1];
                    s2 += hv * fwv[j][2];
                }
                #pragma unroll
                for (int m = 1; m < 16; m <<= 1) {
                    s0 += __shfl_xor(s0, m, 16);
                    s1 += __shfl_xor(s1, m, 16);
                    s2 += __shfl_xor(s2, m, 16);
                }
                if ((lane & 15) == 0) {
                    int trow = (wr << 7) + ((lane >> 4) << 2) + (i << 4) + r;
                    atomicAdd(&t_lds[trow * 3 + 0], s0);
                    atomicAdd(&t_lds[trow * 3 + 1], s1);
                    atomicAdd(&t_lds[trow * 3 + 2], s2);
                }
            }
        }
        __syncthreads();
        const int f3 = (col0 >= DI_) ? 3 : 0;
        for (int z = tid; z < 768; z += 512) {
            int rr = z / 3, k = z - rr * 3;
            atomicAdd(&t_g[(size_t)(row0 + rr) * 6 + f3 + k], t_lds[z]);
        }
    } else {
        const int crow0 = row0 + (wr << 7) + ((lane >> 4) << 2);
        #pragma unroll
        for (int j = 0; j < 4; ++j) {
            int col = col0 + colt0 + j * 16;
            float bs = bias[col];
            #pragma unroll
            for (int i = 0; i < 8; ++i) {
                int rbase = crow0 + i * 16;
                #pragma unroll
                for (int r = 0; r < 4; ++r)
                    C[(size_t)(rbase + r) * NDIM + col] = acc[i][j][r] + bs;
            }
        }
    }
#undef TILE_BODY
#undef PHASE_SYNC
#undef STAGE_A
#undef STAGE_B
}

// ---------------------------------------------------------------------------
// Filt finish: 64 blocks x 256. Thread -> pair p (row = p>>1, f = p&1):
// tanh(t_g[row][f][k] + fb[k]) -> LDS part -> 3 global atomics per block.
// ---------------------------------------------------------------------------
__global__ void filt_finish_k(const float* __restrict__ t_g, const float* __restrict__ fb,
                              float* __restrict__ wacc) {
    __shared__ float part[3];
    const int tid = threadIdx.x;
    if (tid < 3) part[tid] = 0.0f;
    __syncthreads();
    int p = blockIdx.x * 256 + tid;
    int row = p >> 1, f = p & 1;
    const float* tp = t_g + (size_t)row * 6 + f * 3;
    atomicAdd(&part[0], tanhf(tp[0] + fb[0]));
    atomicAdd(&part[1], tanhf(tp[1] + fb[1]));
    atomicAdd(&part[2], tanhf(tp[2] + fb[2]));
    __syncthreads();
    if (tid < 3) {
        int b = blockIdx.x >> 4;     // 16 blocks per batch
        atomicAdd(&wacc[b * 3 + tid], part[tid]);
    }
}

// ---------------------------------------------------------------------------
// Gate, strip-mined: g[r,d] = gelu(conv3_w(xs)[r,d] * v[r,d]), w = wacc/S.
// ---------------------------------------------------------------------------
__global__ void gate_k(const u16* __restrict__ xs, const float* __restrict__ v,
                       const float* __restrict__ wacc, u16* __restrict__ g) {
    const int c = blockIdx.x * 1024 + threadIdx.x * 4;
    const int r0 = blockIdx.y * STRIP;
    const int t0 = r0 & (S_ - 1);
    const int b = r0 >> 11;
    const float w0 = wacc[b * 3 + 0] * (1.0f / (float)S_);
    const float w1 = wacc[b * 3 + 1] * (1.0f / (float)S_);
    const float w2 = wacc[b * 3 + 2] * (1.0f / (float)S_);

    const u16* base = xs + (size_t)r0 * D_ + c;
    f32x4 m2, m1;
    if (t0 == 0) {
        m2 = (f32x4)(0.0f); m1 = (f32x4)(0.0f);
    } else {
        u16x4 a2 = *(const u16x4*)(base - 2 * D_);
        u16x4 a1 = *(const u16x4*)(base - D_);
        #pragma unroll
        for (int e = 0; e < 4; ++e) { m2[e] = b2f(a2[e]); m1[e] = b2f(a1[e]); }
    }

    const float* vp = v + (size_t)r0 * D_ + c;
    u16* op = g + (size_t)r0 * D_ + c;
    #pragma unroll
    for (int rr = 0; rr < STRIP; ++rr) {
        u16x4 cb = *(const u16x4*)(base + (size_t)rr * D_);
        f32x4 vv = *(const f32x4*)(vp + (size_t)rr * D_);
        f32x4 cur;
        #pragma unroll
        for (int e = 0; e < 4; ++e) cur[e] = b2f(cb[e]);
        u16x4 outv;
        #pragma unroll
        for (int e = 0; e < 4; ++e) {
            float conv = w0 * m2[e] + w1 * m1[e] + w2 * cur[e];
            outv[e] = f2b(gelu_exact(conv * vv[e]));
        }
        *(u16x4*)(op + (size_t)rr * D_) = outv;
        m2 = m1; m1 = cur;
    }
}

// ---------------------------------------------------------------------------
extern "C" void kernel_launch(void* const* d_in, const int* in_sizes, int n_in,
                              void* d_out, int out_size, void* d_ws, size_t ws_size,
                              hipStream_t stream) {
    const float* x       = (const float*)d_in[0];
    const float* short_w = (const float*)d_in[1];
    const float* short_b = (const float*)d_in[2];
    const float* proj_w  = (const float*)d_in[3];
    const float* proj_b  = (const float*)d_in[4];
    const float* filt_w  = (const float*)d_in[5];
    const float* filt_b  = (const float*)d_in[6];
    const float* out_w   = (const float*)d_in[7];
    const float* out_b   = (const float*)d_in[8];
    float* out = (float*)d_out;

    // ws: wacc | t_g | xs bf16 32MB | g bf16 32MB | wT1 8MB [| wT2 8MB]
    char* ws = (char*)d_ws;
    const size_t xs_bytes = (size_t)MROWS * D_ * 2;   // 33,554,432
    const size_t wt_bytes = (size_t)KDIM * NDIM * 2;  // 8,388,608
    float* wacc = (float*)(ws);
    float* t_g  = (float*)(ws + 1024);                // 8192*6 fp32
    u16*   xs   = (u16*)(ws + 262144);
    u16*   g    = (u16*)(ws + 262144 + xs_bytes);
    u16*   wT1  = (u16*)(ws + 262144 + 2 * xs_bytes);
    const size_t need_dual = 262144 + 2 * xs_bytes + 2 * wt_bytes;
    const bool dual = (ws_size >= need_dual);
    u16* wT2 = dual ? (u16*)(ws + 262144 + 2 * xs_bytes + wt_bytes) : wT1;

    dim3 tb(32, 8, 1);

    if (dual) {
        dim3 tg(D_ / 32, D_ / 32, 2);
        transpose_k<<<tg, tb, 0, stream>>>(proj_w, wT1, out_w, wT2, D_);
    } else {
        dim3 tg(D_ / 32, D_ / 32, 1);
        transpose_k<<<tg, tb, 0, stream>>>(proj_w, wT1, proj_w, wT1, D_);
    }

    dim3 cg(2, MROWS / STRIP, 1);   // 1024 blocks
    shortconv_k<<<cg, 256, 0, stream>>>(x, short_w, short_b, xs, wacc, t_g);

    dim3 gg(NDIM / 256, MROWS / 256, 1);     // (8, 32) = 256 blocks, 1/CU
    gemm_k<true><<<gg, 512, 0, stream>>>(xs, wT1, proj_b, nullptr, filt_w, t_g,
                                         MROWS, NDIM, KDIM);

    filt_finish_k<<<64, 256, 0, stream>>>(t_g, filt_b, wacc);

    if (!dual) {
        dim3 tg(D_ / 32, D_ / 32, 1);
        transpose_k<<<tg, tb, 0, stream>>>(out_w, wT2, out_w, wT2, D_);
    }

    gate_k<<<cg, 256, 0, stream>>>(xs, x, wacc, g);

    gemm_k<false><<<gg, 512, 0, stream>>>(g, wT2, out_b, out, nullptr, nullptr,
                                          MROWS, NDIM, KDIM);
}

// Round 2
// 365.315 us; speedup vs baseline: 1.5618x; 1.5618x over previous
//
#include <hip/hip_runtime.h>
#include <hip/hip_bf16.h>
#include <math.h>

typedef unsigned short u16;
typedef __attribute__((ext_vector_type(4))) unsigned short u16x4;
typedef __attribute__((ext_vector_type(8))) unsigned short u16x8;
typedef __attribute__((ext_vector_type(8))) short s16x8;
typedef __attribute__((ext_vector_type(4))) float f32x4;

#define B_  4
#define S_  2048
#define D_  2048
#define DI_ 1024
#define MROWS (B_ * S_)          // 8192
#define KDIM  D_                 // 2048
#define NDIM  D_                 // 2048
#define STRIP 16                 // rows per conv strip (divides S_)

__device__ __forceinline__ float b2f(u16 u) {
    union { unsigned i; float f; } v; v.i = ((unsigned)u) << 16; return v.f;
}
__device__ __forceinline__ u16 f2b(float f) {
    unsigned u = __float_as_uint(f);
    unsigned r = (u + 0x7FFFu + ((u >> 16) & 1u)) >> 16;
    return (u16)r;
}
__device__ __forceinline__ float gelu_exact(float x) {
    return 0.5f * x * (1.0f + erff(x * 0.70710678118654752f));
}

#define GLOAD_LDS16(gp, lp)                                                    \
    __builtin_amdgcn_global_load_lds(                                          \
        (const __attribute__((address_space(1))) void*)(gp),                   \
        (__attribute__((address_space(3))) void*)(lp), 16, 0, 0)

// ---------------------------------------------------------------------------
// Transpose n x n, fp32 in -> bf16 out. blockIdx.z picks src/dst when dual.
// ---------------------------------------------------------------------------
__global__ void transpose_k(const float* __restrict__ in0, u16* __restrict__ out0,
                            const float* __restrict__ in1, u16* __restrict__ out1,
                            int n) {
    __shared__ float tile[32][33];
    const float* in = (blockIdx.z == 0) ? in0 : in1;
    u16* out = (blockIdx.z == 0) ? out0 : out1;
    int bx = blockIdx.x * 32, by = blockIdx.y * 32;
    int tx = threadIdx.x, ty = threadIdx.y;
    for (int i = 0; i < 32; i += 8)
        tile[ty + i][tx] = in[(size_t)(by + ty + i) * n + bx + tx];
    __syncthreads();
    for (int i = 0; i < 32; i += 8)
        out[(size_t)(bx + ty + i) * n + by + tx] = f2b(tile[tx][ty + i]);
}

// ---------------------------------------------------------------------------
// Short conv, strip-mined (fp32 in, bf16 out). Also zeroes wacc and t_g.
// ---------------------------------------------------------------------------
__global__ void shortconv_k(const float* __restrict__ x, const float* __restrict__ sw,
                            const float* __restrict__ sb, u16* __restrict__ xs,
                            float* __restrict__ wacc, float* __restrict__ t_g) {
    const int bid = blockIdx.y * 2 + blockIdx.x;
    {
        int z = bid * 256 + threadIdx.x;
        if (z < 12) wacc[z] = 0.0f;
        if (z < MROWS * 6) t_g[z] = 0.0f;
    }
    const int c = blockIdx.x * 1024 + threadIdx.x * 4;
    const int r0 = blockIdx.y * STRIP;
    const int t0 = r0 & (S_ - 1);

    float tap[12];
    #pragma unroll
    for (int q = 0; q < 3; ++q)
        ((f32x4*)tap)[q] = *(const f32x4*)(sw + (size_t)c * 3 + q * 4);
    f32x4 sbv = *(const f32x4*)(sb + c);

    const float* base = x + (size_t)r0 * D_ + c;
    f32x4 m2, m1;
    if (t0 == 0) { m2 = (f32x4)(0.0f); m1 = (f32x4)(0.0f); }
    else { m2 = *(const f32x4*)(base - 2 * D_); m1 = *(const f32x4*)(base - D_); }

    u16* op = xs + (size_t)r0 * D_ + c;
    #pragma unroll
    for (int rr = 0; rr < STRIP; ++rr) {
        f32x4 cur = *(const f32x4*)(base + (size_t)rr * D_);
        u16x4 outv;
        #pragma unroll
        for (int e = 0; e < 4; ++e) {
            float v = cur[e] + sbv[e]
                    + tap[e * 3 + 0] * m2[e]
                    + tap[e * 3 + 1] * m1[e]
                    + tap[e * 3 + 2] * cur[e];
            outv[e] = f2b(v);
        }
        *(u16x4*)(op + (size_t)rr * D_) = outv;
        m2 = m1; m1 = cur;
    }
}

// ---------------------------------------------------------------------------
// GEMM1 (FILT): proven round-0 structure. 128x128 tile, BK=32, 4 waves,
// 4x4 MFMA 16x16x32 per wave, global_load_lds width-16 with XOR swizzle.
// Epilogue folds gelu(acc+bias) with fw into per-row partials t_g.
// ---------------------------------------------------------------------------
__global__ void gemm_f(const u16* __restrict__ A, const u16* __restrict__ BT,
                       const float* __restrict__ bias,
                       const float* __restrict__ fw, float* __restrict__ t_g,
                       int K) {
    __shared__ u16 As[128 * 32];
    __shared__ u16 Bs[128 * 32];
    __shared__ float t_lds[128 * 3];
    const int tid = threadIdx.x;
    const int wid = tid >> 6;
    const int lane = tid & 63;
    const int wm = (wid >> 1) * 64;
    const int wn = (wid & 1) * 64;
    const int row0 = blockIdx.y * 128;
    const int col0 = blockIdx.x * 128;

    for (int z = tid; z < 384; z += 256) t_lds[z] = 0.0f;

    f32x4 acc[4][4];
    #pragma unroll
    for (int i = 0; i < 4; ++i)
        #pragma unroll
        for (int j = 0; j < 4; ++j) acc[i][j] = (f32x4)(0.0f);

    const int srow_l = lane >> 2;
    const int cs = lane & 3;
    const int mrow = wm + (lane & 15);
    const int nrow = wn + (lane & 15);
    const int cf = lane >> 4;

    for (int kt = 0; kt < K; kt += 32) {
        __syncthreads();
        #pragma unroll
        for (int p = 0; p < 2; ++p) {
            int srow = p * 64 + wid * 16 + srow_l;
            int gc = cs ^ ((srow >> 1) & 3);
            u16* lpa = &As[(p * 4 + wid) * 512];
            u16* lpb = &Bs[(p * 4 + wid) * 512];
            const u16* ga = A + (size_t)(row0 + srow) * K + kt + gc * 8;
            const u16* gb = BT + (size_t)(col0 + srow) * K + kt + gc * 8;
            GLOAD_LDS16(ga, lpa);
            GLOAD_LDS16(gb, lpb);
        }
        __syncthreads();

        s16x8 af[4], bfr[4];
        #pragma unroll
        for (int i = 0; i < 4; ++i) {
            int ra = mrow + i * 16;
            af[i] = *(const s16x8*)&As[ra * 32 + ((cf ^ ((ra >> 1) & 3)) * 8)];
        }
        #pragma unroll
        for (int j = 0; j < 4; ++j) {
            int rb = nrow + j * 16;
            bfr[j] = *(const s16x8*)&Bs[rb * 32 + ((cf ^ ((rb >> 1) & 3)) * 8)];
        }
        #pragma unroll
        for (int i = 0; i < 4; ++i)
            #pragma unroll
            for (int j = 0; j < 4; ++j)
                acc[i][j] = __builtin_amdgcn_mfma_f32_16x16x32_bf16(
                    af[i], bfr[j], acc[i][j], 0, 0, 0);
    }

    const int colt0 = wn + (lane & 15);
    float fwv[4][3], bsv[4];
    const int ibase = (col0 & (DI_ - 1)) + colt0;
    #pragma unroll
    for (int j = 0; j < 4; ++j) {
        int ifilt = ibase + j * 16;
        fwv[j][0] = fw[ifilt * 3 + 0];
        fwv[j][1] = fw[ifilt * 3 + 1];
        fwv[j][2] = fw[ifilt * 3 + 2];
        bsv[j] = bias[col0 + colt0 + j * 16];
    }
    #pragma unroll
    for (int i = 0; i < 4; ++i) {
        #pragma unroll
        for (int r = 0; r < 4; ++r) {
            float s0 = 0.f, s1 = 0.f, s2 = 0.f;
            #pragma unroll
            for (int j = 0; j < 4; ++j) {
                float hv = gelu_exact(acc[i][j][r] + bsv[j]);
                s0 += hv * fwv[j][0];
                s1 += hv * fwv[j][1];
                s2 += hv * fwv[j][2];
            }
            #pragma unroll
            for (int m = 1; m < 16; m <<= 1) {
                s0 += __shfl_xor(s0, m, 16);
                s1 += __shfl_xor(s1, m, 16);
                s2 += __shfl_xor(s2, m, 16);
            }
            if ((lane & 15) == 0) {
                int trow = wm + (lane >> 4) * 4 + i * 16 + r;
                atomicAdd(&t_lds[trow * 3 + 0], s0);
                atomicAdd(&t_lds[trow * 3 + 1], s1);
                atomicAdd(&t_lds[trow * 3 + 2], s2);
            }
        }
    }
    __syncthreads();
    const int f3 = (col0 >= DI_) ? 3 : 0;
    for (int z = tid; z < 384; z += 256) {
        int rr = z / 3, k = z - rr * 3;
        atomicAdd(&t_g[(size_t)(row0 + rr) * 6 + f3 + k], t_lds[z]);
    }
}

// ---------------------------------------------------------------------------
// GEMM2 (plain): 256x256 tile, BK=64 dbuf split into k-half regions.
// m201-faithful 8-phase schedule: per phase {4-or-8 ds_read_b128 || 1
// half-tile stage (2 global_load_lds) -> s_barrier -> lgkmcnt(0) ->
// sched_barrier(0) -> setprio(1) 16 MFMA setprio(0) -> s_barrier};
// counted vmcnt(4) only at phases 4 and 8. Regions compile-time.
// Region r = buf*2+s holds 256 rows x 32 k (16 KiB each; 128 KiB total).
// Stage schedule (iter t, kb=t*128 elems):
//   P1:A(2t+1)[s1]->As3  P2:B->Bs3  P3:A(2t+2)[s0]->As0  P4:B->Bs0
//   P5:A(2t+2)[s1]->As1  P6:B->Bs1  P7:A(2t+3)[s0]->As2  P8:B->Bs2
// WAR-safe (target region's last read >=1 phase-pair earlier, collective
// barriers between); completion deadlines covered by vmcnt(4)@P4/P8.
// ---------------------------------------------------------------------------
__global__ __launch_bounds__(512, 2)
void gemm8_k(const u16* __restrict__ A, const u16* __restrict__ BT,
             const float* __restrict__ bias, float* __restrict__ C) {
    __shared__ u16 As[4][8192];
    __shared__ u16 Bs[4][8192];

    const int tid  = threadIdx.x;
    const int wid  = tid >> 6;
    const int lane = tid & 63;
    const int wr   = wid >> 2;             // 0..1 : 128-row half
    const int wc   = wid & 3;              // 0..3 : 64-col quarter
    const int row0 = blockIdx.y << 8;
    const int col0 = blockIdx.x << 8;

    // staging: thread covers 16B at linear slot q*512+tid of a half-tile
    const int rowS    = tid >> 2;                                   // 0..127
    const int colOffS = (((tid & 3) ^ ((rowS >> 1) & 3)) << 3);     // elems
    const u16* gA = A  + (size_t)(row0 + rowS) * KDIM + colOffS;
    const u16* gB = BT + (size_t)(col0 + rowS) * KDIM + colOffS;
    const int ldsW0 = wid * 512;            // u16 units (q=0)
    const int ldsW1 = 4096 + wid * 512;     // q=1

    // fragment ds_read offsets within a region (u16 units), XOR-swizzled
    int aoffR[8], boffR[4];
    #pragma unroll
    for (int i = 0; i < 8; ++i) {
        int row  = (wr << 7) + (i << 4) + (lane & 15);
        int slot = (lane >> 4) ^ ((row >> 1) & 3);
        aoffR[i] = row * 32 + slot * 8;
    }
    #pragma unroll
    for (int j = 0; j < 4; ++j) {
        int row  = (wc << 6) + (j << 4) + (lane & 15);
        int slot = (lane >> 4) ^ ((row >> 1) & 3);
        boffR[j] = row * 32 + slot * 8;
    }

    f32x4 acc[8][4];
    #pragma unroll
    for (int i = 0; i < 8; ++i)
        #pragma unroll
        for (int j = 0; j < 4; ++j) acc[i][j] = (f32x4)(0.0f);

    s16x8 af[4], bf[4];

#define STG_A(REG, KOFF) do { const u16* _g = gA + (KOFF);                     \
    GLOAD_LDS16(_g, &As[REG][ldsW0]);                                          \
    GLOAD_LDS16(_g + (size_t)128 * KDIM, &As[REG][ldsW1]); } while (0)
#define STG_B(REG, KOFF) do { const u16* _g = gB + (KOFF);                     \
    GLOAD_LDS16(_g, &Bs[REG][ldsW0]);                                          \
    GLOAD_LDS16(_g + (size_t)128 * KDIM, &Bs[REG][ldsW1]); } while (0)
#define LD_B4(REG) do {                                                        \
    bf[0] = *(const s16x8*)&Bs[REG][boffR[0]];                                 \
    bf[1] = *(const s16x8*)&Bs[REG][boffR[1]];                                 \
    bf[2] = *(const s16x8*)&Bs[REG][boffR[2]];                                 \
    bf[3] = *(const s16x8*)&Bs[REG][boffR[3]]; } while (0)
#define LD_A4(REG, I0) do {                                                    \
    af[0] = *(const s16x8*)&As[REG][aoffR[(I0) + 0]];                          \
    af[1] = *(const s16x8*)&As[REG][aoffR[(I0) + 1]];                          \
    af[2] = *(const s16x8*)&As[REG][aoffR[(I0) + 2]];                          \
    af[3] = *(const s16x8*)&As[REG][aoffR[(I0) + 3]]; } while (0)
#define SYNC_IN() do { __builtin_amdgcn_s_barrier();                           \
    asm volatile("s_waitcnt lgkmcnt(0)" ::: "memory");                         \
    __builtin_amdgcn_sched_barrier(0); } while (0)
#define MFMA16(I0) do { __builtin_amdgcn_s_setprio(1);                         \
    _Pragma("unroll")                                                          \
    for (int i_ = 0; i_ < 4; ++i_) {                                           \
        _Pragma("unroll")                                                      \
        for (int j_ = 0; j_ < 4; ++j_)                                         \
            acc[(I0) + i_][j_] = __builtin_amdgcn_mfma_f32_16x16x32_bf16(      \
                af[i_], bf[j_], acc[(I0) + i_][j_], 0, 0, 0);                  \
    }                                                                          \
    __builtin_amdgcn_s_setprio(0); } while (0)
#define BARR() __builtin_amdgcn_s_barrier()
#define VM4() asm volatile("s_waitcnt vmcnt(4)" ::: "memory")
#define VM0() asm volatile("s_waitcnt vmcnt(0)" ::: "memory")

    // prologue: tile0 both halves + tile1 s0 (6 half-tiles, 12 loads)
    STG_A(0, 0);  STG_B(0, 0);
    STG_A(1, 32); STG_B(1, 32);
    STG_A(2, 64); STG_B(2, 64);
    VM4();                       // tile0 halves landed; tile1[s0] in flight
    BARR();

    #pragma unroll 1
    for (int t = 0; t < 15; ++t) {
        const int kb = t * 128;
        LD_B4(0); LD_A4(0, 0); STG_A(3, kb + 96);  SYNC_IN(); MFMA16(0); BARR();
        LD_A4(0, 4);           STG_B(3, kb + 96);  SYNC_IN(); MFMA16(4); BARR();
        LD_B4(1); LD_A4(1, 0); STG_A(0, kb + 128); SYNC_IN(); MFMA16(0); BARR();
        LD_A4(1, 4);           STG_B(0, kb + 128); SYNC_IN(); MFMA16(4); VM4(); BARR();
        LD_B4(2); LD_A4(2, 0); STG_A(1, kb + 160); SYNC_IN(); MFMA16(0); BARR();
        LD_A4(2, 4);           STG_B(1, kb + 160); SYNC_IN(); MFMA16(4); BARR();
        LD_B4(3); LD_A4(3, 0); STG_A(2, kb + 192); SYNC_IN(); MFMA16(0); BARR();
        LD_A4(3, 4);           STG_B(2, kb + 192); SYNC_IN(); MFMA16(4); VM4(); BARR();
    }
    {   // final iteration t=15: only P1/P2 stage (tile31[s1]); drain at P4
        const int kb = 15 * 128;
        LD_B4(0); LD_A4(0, 0); STG_A(3, kb + 96);  SYNC_IN(); MFMA16(0); BARR();
        LD_A4(0, 4);           STG_B(3, kb + 96);  SYNC_IN(); MFMA16(4); BARR();
        LD_B4(1); LD_A4(1, 0);                     SYNC_IN(); MFMA16(0); BARR();
        LD_A4(1, 4);                               SYNC_IN(); MFMA16(4); VM0(); BARR();
        LD_B4(2); LD_A4(2, 0);                     SYNC_IN(); MFMA16(0); BARR();
        LD_A4(2, 4);                               SYNC_IN(); MFMA16(4); BARR();
        LD_B4(3); LD_A4(3, 0);                     SYNC_IN(); MFMA16(0); BARR();
        LD_A4(3, 4);                               SYNC_IN(); MFMA16(4); BARR();
    }

    // C write: row = row0 + wr*128 + (lane>>4)*4 + i*16 + r,
    //          col = col0 + wc*64 + (lane&15) + j*16
    const int colt0 = (wc << 6) + (lane & 15);
    const int crow0 = row0 + (wr << 7) + ((lane >> 4) << 2);
    #pragma unroll
    for (int j = 0; j < 4; ++j) {
        int col = col0 + colt0 + j * 16;
        float bs = bias[col];
        #pragma unroll
        for (int i = 0; i < 8; ++i) {
            int rbase = crow0 + i * 16;
            #pragma unroll
            for (int r = 0; r < 4; ++r)
                C[(size_t)(rbase + r) * NDIM + col] = acc[i][j][r] + bs;
        }
    }
#undef STG_A
#undef STG_B
#undef LD_B4
#undef LD_A4
#undef SYNC_IN
#undef MFMA16
#undef BARR
#undef VM4
#undef VM0
}

// ---------------------------------------------------------------------------
// Filt finish: tanh(t_g + fb) -> per-block LDS partials -> wacc atomics.
// ---------------------------------------------------------------------------
__global__ void filt_finish_k(const float* __restrict__ t_g, const float* __restrict__ fb,
                              float* __restrict__ wacc) {
    __shared__ float part[3];
    const int tid = threadIdx.x;
    if (tid < 3) part[tid] = 0.0f;
    __syncthreads();
    int p = blockIdx.x * 256 + tid;
    int row = p >> 1, f = p & 1;
    const float* tp = t_g + (size_t)row * 6 + f * 3;
    atomicAdd(&part[0], tanhf(tp[0] + fb[0]));
    atomicAdd(&part[1], tanhf(tp[1] + fb[1]));
    atomicAdd(&part[2], tanhf(tp[2] + fb[2]));
    __syncthreads();
    if (tid < 3) {
        int b = blockIdx.x >> 4;     // 16 blocks per batch
        atomicAdd(&wacc[b * 3 + tid], part[tid]);
    }
}

// ---------------------------------------------------------------------------
// Gate, strip-mined: g[r,d] = gelu(conv3_w(xs)[r,d] * v[r,d]), w = wacc/S.
// ---------------------------------------------------------------------------
__global__ void gate_k(const u16* __restrict__ xs, const float* __restrict__ v,
                       const float* __restrict__ wacc, u16* __restrict__ g) {
    const int c = blockIdx.x * 1024 + threadIdx.x * 4;
    const int r0 = blockIdx.y * STRIP;
    const int t0 = r0 & (S_ - 1);
    const int b = r0 >> 11;
    const float w0 = wacc[b * 3 + 0] * (1.0f / (float)S_);
    const float w1 = wacc[b * 3 + 1] * (1.0f / (float)S_);
    const float w2 = wacc[b * 3 + 2] * (1.0f / (float)S_);

    const u16* base = xs + (size_t)r0 * D_ + c;
    f32x4 m2, m1;
    if (t0 == 0) {
        m2 = (f32x4)(0.0f); m1 = (f32x4)(0.0f);
    } else {
        u16x4 a2 = *(const u16x4*)(base - 2 * D_);
        u16x4 a1 = *(const u16x4*)(base - D_);
        #pragma unroll
        for (int e = 0; e < 4; ++e) { m2[e] = b2f(a2[e]); m1[e] = b2f(a1[e]); }
    }

    const float* vp = v + (size_t)r0 * D_ + c;
    u16* op = g + (size_t)r0 * D_ + c;
    #pragma unroll
    for (int rr = 0; rr < STRIP; ++rr) {
        u16x4 cb = *(const u16x4*)(base + (size_t)rr * D_);
        f32x4 vv = *(const f32x4*)(vp + (size_t)rr * D_);
        f32x4 cur;
        #pragma unroll
        for (int e = 0; e < 4; ++e) cur[e] = b2f(cb[e]);
        u16x4 outv;
        #pragma unroll
        for (int e = 0; e < 4; ++e) {
            float conv = w0 * m2[e] + w1 * m1[e] + w2 * cur[e];
            outv[e] = f2b(gelu_exact(conv * vv[e]));
        }
        *(u16x4*)(op + (size_t)rr * D_) = outv;
        m2 = m1; m1 = cur;
    }
}

// ---------------------------------------------------------------------------
extern "C" void kernel_launch(void* const* d_in, const int* in_sizes, int n_in,
                              void* d_out, int out_size, void* d_ws, size_t ws_size,
                              hipStream_t stream) {
    const float* x       = (const float*)d_in[0];
    const float* short_w = (const float*)d_in[1];
    const float* short_b = (const float*)d_in[2];
    const float* proj_w  = (const float*)d_in[3];
    const float* proj_b  = (const float*)d_in[4];
    const float* filt_w  = (const float*)d_in[5];
    const float* filt_b  = (const float*)d_in[6];
    const float* out_w   = (const float*)d_in[7];
    const float* out_b   = (const float*)d_in[8];
    float* out = (float*)d_out;

    // ws: wacc | t_g | xs bf16 32MB | g bf16 32MB | wT1 8MB [| wT2 8MB]
    char* ws = (char*)d_ws;
    const size_t xs_bytes = (size_t)MROWS * D_ * 2;   // 33,554,432
    const size_t wt_bytes = (size_t)KDIM * NDIM * 2;  // 8,388,608
    float* wacc = (float*)(ws);
    float* t_g  = (float*)(ws + 1024);                // 8192*6 fp32
    u16*   xs   = (u16*)(ws + 262144);
    u16*   g    = (u16*)(ws + 262144 + xs_bytes);
    u16*   wT1  = (u16*)(ws + 262144 + 2 * xs_bytes);
    const size_t need_dual = 262144 + 2 * xs_bytes + 2 * wt_bytes;
    const bool dual = (ws_size >= need_dual);
    u16* wT2 = dual ? (u16*)(ws + 262144 + 2 * xs_bytes + wt_bytes) : wT1;

    dim3 tb(32, 8, 1);

    if (dual) {
        dim3 tg(D_ / 32, D_ / 32, 2);
        transpose_k<<<tg, tb, 0, stream>>>(proj_w, wT1, out_w, wT2, D_);
    } else {
        dim3 tg(D_ / 32, D_ / 32, 1);
        transpose_k<<<tg, tb, 0, stream>>>(proj_w, wT1, proj_w, wT1, D_);
    }

    dim3 cg(2, MROWS / STRIP, 1);   // 1024 blocks
    shortconv_k<<<cg, 256, 0, stream>>>(x, short_w, short_b, xs, wacc, t_g);

    dim3 gf(NDIM / 128, MROWS / 128, 1);     // (16, 64)
    gemm_f<<<gf, 256, 0, stream>>>(xs, wT1, proj_b, filt_w, t_g, KDIM);

    filt_finish_k<<<64, 256, 0, stream>>>(t_g, filt_b, wacc);

    if (!dual) {
        dim3 tg(D_ / 32, D_ / 32, 1);
        transpose_k<<<tg, tb, 0, stream>>>(out_w, wT2, out_w, wT2, D_);
    }

    gate_k<<<cg, 256, 0, stream>>>(xs, x, wacc, g);

    dim3 g8(NDIM / 256, MROWS / 256, 1);     // (8, 32) = 256 blocks, 1/CU
    gemm8_k<<<g8, 512, 0, stream>>>(g, wT2, out_b, out);
}

// Round 3
// 361.994 us; speedup vs baseline: 1.5762x; 1.0092x over previous
//
#include <hip/hip_runtime.h>
#include <hip/hip_bf16.h>
#include <math.h>

typedef unsigned short u16;
typedef __attribute__((ext_vector_type(4))) unsigned short u16x4;
typedef __attribute__((ext_vector_type(8))) unsigned short u16x8;
typedef __attribute__((ext_vector_type(8))) short s16x8;
typedef __attribute__((ext_vector_type(4))) float f32x4;

#define B_  4
#define S_  2048
#define D_  2048
#define DI_ 1024
#define MROWS (B_ * S_)          // 8192
#define KDIM  D_                 // 2048
#define NDIM  D_                 // 2048
#define STRIP 16                 // rows per conv strip (divides S_)

__device__ __forceinline__ float b2f(u16 u) {
    union { unsigned i; float f; } v; v.i = ((unsigned)u) << 16; return v.f;
}
__device__ __forceinline__ u16 f2b(float f) {
    unsigned u = __float_as_uint(f);
    unsigned r = (u + 0x7FFFu + ((u >> 16) & 1u)) >> 16;
    return (u16)r;
}
__device__ __forceinline__ float gelu_exact(float x) {
    return 0.5f * x * (1.0f + erff(x * 0.70710678118654752f));
}

#define GLOAD_LDS16(gp, lp)                                                    \
    __builtin_amdgcn_global_load_lds(                                          \
        (const __attribute__((address_space(1))) void*)(gp),                   \
        (__attribute__((address_space(3))) void*)(lp), 16, 0, 0)

// ---------------------------------------------------------------------------
// Transpose n x n, fp32 in -> bf16 out. blockIdx.z picks src/dst when dual.
// ---------------------------------------------------------------------------
__global__ void transpose_k(const float* __restrict__ in0, u16* __restrict__ out0,
                            const float* __restrict__ in1, u16* __restrict__ out1,
                            int n) {
    __shared__ float tile[32][33];
    const float* in = (blockIdx.z == 0) ? in0 : in1;
    u16* out = (blockIdx.z == 0) ? out0 : out1;
    int bx = blockIdx.x * 32, by = blockIdx.y * 32;
    int tx = threadIdx.x, ty = threadIdx.y;
    for (int i = 0; i < 32; i += 8)
        tile[ty + i][tx] = in[(size_t)(by + ty + i) * n + bx + tx];
    __syncthreads();
    for (int i = 0; i < 32; i += 8)
        out[(size_t)(bx + ty + i) * n + by + tx] = f2b(tile[tx][ty + i]);
}

// ---------------------------------------------------------------------------
// Short conv, strip-mined (fp32 in, bf16 out). Also zeroes wacc and t_g.
// ---------------------------------------------------------------------------
__global__ void shortconv_k(const float* __restrict__ x, const float* __restrict__ sw,
                            const float* __restrict__ sb, u16* __restrict__ xs,
                            float* __restrict__ wacc, float* __restrict__ t_g) {
    const int bid = blockIdx.y * 2 + blockIdx.x;
    {
        int z = bid * 256 + threadIdx.x;
        if (z < 12) wacc[z] = 0.0f;
        if (z < MROWS * 6) t_g[z] = 0.0f;
    }
    const int c = blockIdx.x * 1024 + threadIdx.x * 4;
    const int r0 = blockIdx.y * STRIP;
    const int t0 = r0 & (S_ - 1);

    float tap[12];
    #pragma unroll
    for (int q = 0; q < 3; ++q)
        ((f32x4*)tap)[q] = *(const f32x4*)(sw + (size_t)c * 3 + q * 4);
    f32x4 sbv = *(const f32x4*)(sb + c);

    const float* base = x + (size_t)r0 * D_ + c;
    f32x4 m2, m1;
    if (t0 == 0) { m2 = (f32x4)(0.0f); m1 = (f32x4)(0.0f); }
    else { m2 = *(const f32x4*)(base - 2 * D_); m1 = *(const f32x4*)(base - D_); }

    u16* op = xs + (size_t)r0 * D_ + c;
    #pragma unroll
    for (int rr = 0; rr < STRIP; ++rr) {
        f32x4 cur = *(const f32x4*)(base + (size_t)rr * D_);
        u16x4 outv;
        #pragma unroll
        for (int e = 0; e < 4; ++e) {
            float v = cur[e] + sbv[e]
                    + tap[e * 3 + 0] * m2[e]
                    + tap[e * 3 + 1] * m1[e]
                    + tap[e * 3 + 2] * cur[e];
            outv[e] = f2b(v);
        }
        *(u16x4*)(op + (size_t)rr * D_) = outv;
        m2 = m1; m1 = cur;
    }
}

// ===========================================================================
// Shared 256x256 8-phase K-loop (BK=32 regions x4, 128 KiB LDS ring).
// Stage schedule (iter t, kb=t*128): P1:A->r3(kb+96) P2:B->r3 P3:A->r0(kb+128)
// P4:B->r0 P5:A->r1(kb+160) P6:B->r1 P7:A->r2(kb+192) P8:B->r2.
// Readers: P1/P2<-r0, P3/P4<-r1, P5/P6<-r2, P7/P8<-r3 (staged 6 phases prior).
// Waits: vmcnt(8) at end of every even phase -> each stage forced landed
// 4-6 phases after issue (RAW-safe: @P2 forces prev P5/P6 for P3's read;
// @P4 forces prev P7/P8 for P5; @P6 forces cur P1/P2 for P7; @P8 forces
// cur P3/P4 for next P1). WAR-safe: region re-staged in the phase right
// after its last read, across a barrier. Final iter: VM8@P2, VM4@P4, VM0@P6.
// ===========================================================================
#define STG_A(REG, KOFF) do { const u16* _g = gA + (KOFF);                     \
    GLOAD_LDS16(_g, &As[REG][ldsW0]);                                          \
    GLOAD_LDS16(_g + (size_t)128 * KDIM, &As[REG][ldsW1]); } while (0)
#define STG_B(REG, KOFF) do { const u16* _g = gB + (KOFF);                     \
    GLOAD_LDS16(_g, &Bs[REG][ldsW0]);                                          \
    GLOAD_LDS16(_g + (size_t)128 * KDIM, &Bs[REG][ldsW1]); } while (0)
#define LD_B4(REG) do {                                                        \
    bf[0] = *(const s16x8*)&Bs[REG][boffR[0]];                                 \
    bf[1] = *(const s16x8*)&Bs[REG][boffR[1]];                                 \
    bf[2] = *(const s16x8*)&Bs[REG][boffR[2]];                                 \
    bf[3] = *(const s16x8*)&Bs[REG][boffR[3]]; } while (0)
#define LD_A4(REG, I0) do {                                                    \
    af[0] = *(const s16x8*)&As[REG][aoffR[(I0) + 0]];                          \
    af[1] = *(const s16x8*)&As[REG][aoffR[(I0) + 1]];                          \
    af[2] = *(const s16x8*)&As[REG][aoffR[(I0) + 2]];                          \
    af[3] = *(const s16x8*)&As[REG][aoffR[(I0) + 3]]; } while (0)
#define SYNC_IN() do { __builtin_amdgcn_s_barrier();                           \
    asm volatile("s_waitcnt lgkmcnt(0)" ::: "memory");                         \
    __builtin_amdgcn_sched_barrier(0); } while (0)
#define MFMA16(I0) do { __builtin_amdgcn_s_setprio(1);                         \
    _Pragma("unroll")                                                          \
    for (int i_ = 0; i_ < 4; ++i_) {                                           \
        _Pragma("unroll")                                                      \
        for (int j_ = 0; j_ < 4; ++j_)                                         \
            acc[(I0) + i_][j_] = __builtin_amdgcn_mfma_f32_16x16x32_bf16(      \
                af[i_], bf[j_], acc[(I0) + i_][j_], 0, 0, 0);                  \
    }                                                                          \
    __builtin_amdgcn_s_setprio(0); } while (0)
#define BARR() __builtin_amdgcn_s_barrier()
#define VM8() asm volatile("s_waitcnt vmcnt(8)" ::: "memory")
#define VM4() asm volatile("s_waitcnt vmcnt(4)" ::: "memory")
#define VM0() asm volatile("s_waitcnt vmcnt(0)" ::: "memory")

#define GEMM_CORE(APTR, BPTR)                                                  \
    __shared__ u16 As[4][8192];                                                \
    __shared__ u16 Bs[4][8192];                                                \
    const int tid  = threadIdx.x;                                              \
    const int wid  = tid >> 6;                                                 \
    const int lane = tid & 63;                                                 \
    const int wr   = wid >> 2;                                                 \
    const int wc   = wid & 3;                                                  \
    const int row0 = blockIdx.y << 8;                                          \
    const int col0 = blockIdx.x << 8;                                          \
    const int rowS    = tid >> 2;                                              \
    const int colOffS = (((tid & 3) ^ ((rowS >> 1) & 3)) << 3);                \
    const u16* gA = (APTR) + (size_t)(row0 + rowS) * KDIM + colOffS;           \
    const u16* gB = (BPTR) + (size_t)(col0 + rowS) * KDIM + colOffS;           \
    const int ldsW0 = wid * 512;                                               \
    const int ldsW1 = 4096 + wid * 512;                                        \
    int aoffR[8], boffR[4];                                                    \
    _Pragma("unroll")                                                          \
    for (int i = 0; i < 8; ++i) {                                              \
        int row  = (wr << 7) + (i << 4) + (lane & 15);                         \
        int slot = (lane >> 4) ^ ((row >> 1) & 3);                             \
        aoffR[i] = row * 32 + slot * 8;                                        \
    }                                                                          \
    _Pragma("unroll")                                                          \
    for (int j = 0; j < 4; ++j) {                                              \
        int row  = (wc << 6) + (j << 4) + (lane & 15);                         \
        int slot = (lane >> 4) ^ ((row >> 1) & 3);                             \
        boffR[j] = row * 32 + slot * 8;                                        \
    }                                                                          \
    f32x4 acc[8][4];                                                           \
    _Pragma("unroll")                                                          \
    for (int i = 0; i < 8; ++i)                                                \
        _Pragma("unroll")                                                      \
        for (int j = 0; j < 4; ++j) acc[i][j] = (f32x4)(0.0f);                 \
    s16x8 af[4], bf[4];                                                        \
    STG_A(0, 0);  STG_B(0, 0);                                                 \
    STG_A(1, 32); STG_B(1, 32);                                                \
    STG_A(2, 64); STG_B(2, 64);                                                \
    VM8();                                                                     \
    BARR();                                                                    \
    _Pragma("unroll 1")                                                        \
    for (int t = 0; t < 15; ++t) {                                             \
        const int kb = t * 128;                                                \
        LD_B4(0); LD_A4(0,0); STG_A(3, kb + 96);  SYNC_IN(); MFMA16(0); BARR();        \
        LD_A4(0,4);           STG_B(3, kb + 96);  SYNC_IN(); MFMA16(4); VM8(); BARR(); \
        LD_B4(1); LD_A4(1,0); STG_A(0, kb + 128); SYNC_IN(); MFMA16(0); BARR();        \
        LD_A4(1,4);           STG_B(0, kb + 128); SYNC_IN(); MFMA16(4); VM8(); BARR(); \
        LD_B4(2); LD_A4(2,0); STG_A(1, kb + 160); SYNC_IN(); MFMA16(0); BARR();        \
        LD_A4(2,4);           STG_B(1, kb + 160); SYNC_IN(); MFMA16(4); VM8(); BARR(); \
        LD_B4(3); LD_A4(3,0); STG_A(2, kb + 192); SYNC_IN(); MFMA16(0); BARR();        \
        LD_A4(3,4);           STG_B(2, kb + 192); SYNC_IN(); MFMA16(4); VM8(); BARR(); \
    }                                                                          \
    {                                                                          \
        const int kb = 15 * 128;                                               \
        LD_B4(0); LD_A4(0,0); STG_A(3, kb + 96);  SYNC_IN(); MFMA16(0); BARR();        \
        LD_A4(0,4);           STG_B(3, kb + 96);  SYNC_IN(); MFMA16(4); VM8(); BARR(); \
        LD_B4(1); LD_A4(1,0);                     SYNC_IN(); MFMA16(0); BARR();        \
        LD_A4(1,4);                               SYNC_IN(); MFMA16(4); VM4(); BARR(); \
        LD_B4(2); LD_A4(2,0);                     SYNC_IN(); MFMA16(0); BARR();        \
        LD_A4(2,4);                               SYNC_IN(); MFMA16(4); VM0(); BARR(); \
        LD_B4(3); LD_A4(3,0);                     SYNC_IN(); MFMA16(0); BARR();        \
        LD_A4(3,4);                               SYNC_IN(); MFMA16(4); BARR();        \
    }

// ---------------------------------------------------------------------------
// GEMM1 (FILT), 8-phase: epilogue folds gelu(acc+bias)*fw into t_g partials.
// ---------------------------------------------------------------------------
__global__ __launch_bounds__(512, 2)
void gemm_f8(const u16* __restrict__ A, const u16* __restrict__ BT,
             const float* __restrict__ bias,
             const float* __restrict__ fw, float* __restrict__ t_g) {
    GEMM_CORE(A, BT)

    __shared__ float t_lds[768];
    __syncthreads();
    for (int z = tid; z < 768; z += 512) t_lds[z] = 0.0f;
    __syncthreads();

    const int colt0 = (wc << 6) + (lane & 15);
    float fwv[4][3], bsv[4];
    const int ibase = (col0 & (DI_ - 1)) + colt0;
    #pragma unroll
    for (int j = 0; j < 4; ++j) {
        int ifilt = ibase + j * 16;
        fwv[j][0] = fw[ifilt * 3 + 0];
        fwv[j][1] = fw[ifilt * 3 + 1];
        fwv[j][2] = fw[ifilt * 3 + 2];
        bsv[j] = bias[col0 + colt0 + j * 16];
    }
    #pragma unroll
    for (int i = 0; i < 8; ++i) {
        #pragma unroll
        for (int r = 0; r < 4; ++r) {
            float s0 = 0.f, s1 = 0.f, s2 = 0.f;
            #pragma unroll
            for (int j = 0; j < 4; ++j) {
                float hv = gelu_exact(acc[i][j][r] + bsv[j]);
                s0 += hv * fwv[j][0];
                s1 += hv * fwv[j][1];
                s2 += hv * fwv[j][2];
            }
            #pragma unroll
            for (int m = 1; m < 16; m <<= 1) {
                s0 += __shfl_xor(s0, m, 16);
                s1 += __shfl_xor(s1, m, 16);
                s2 += __shfl_xor(s2, m, 16);
            }
            if ((lane & 15) == 0) {
                int trow = (wr << 7) + ((lane >> 4) << 2) + (i << 4) + r;
                atomicAdd(&t_lds[trow * 3 + 0], s0);
                atomicAdd(&t_lds[trow * 3 + 1], s1);
                atomicAdd(&t_lds[trow * 3 + 2], s2);
            }
        }
    }
    __syncthreads();
    const int f3 = (col0 >= DI_) ? 3 : 0;
    for (int z = tid; z < 768; z += 512) {
        int rr = z / 3, k = z - rr * 3;
        atomicAdd(&t_g[(size_t)(row0 + rr) * 6 + f3 + k], t_lds[z]);
    }
}

// ---------------------------------------------------------------------------
// GEMM2 (plain), 8-phase: C fp32 = acc + bias.
// ---------------------------------------------------------------------------
__global__ __launch_bounds__(512, 2)
void gemm8_k(const u16* __restrict__ A, const u16* __restrict__ BT,
             const float* __restrict__ bias, float* __restrict__ C) {
    GEMM_CORE(A, BT)

    const int colt0 = (wc << 6) + (lane & 15);
    const int crow0 = row0 + (wr << 7) + ((lane >> 4) << 2);
    #pragma unroll
    for (int j = 0; j < 4; ++j) {
        int col = col0 + colt0 + j * 16;
        float bs = bias[col];
        #pragma unroll
        for (int i = 0; i < 8; ++i) {
            int rbase = crow0 + i * 16;
            #pragma unroll
            for (int r = 0; r < 4; ++r)
                C[(size_t)(rbase + r) * NDIM + col] = acc[i][j][r] + bs;
        }
    }
}

// ---------------------------------------------------------------------------
// Filt finish: tanh(t_g + fb) -> per-block LDS partials -> wacc atomics.
// ---------------------------------------------------------------------------
__global__ void filt_finish_k(const float* __restrict__ t_g, const float* __restrict__ fb,
                              float* __restrict__ wacc) {
    __shared__ float part[3];
    const int tid = threadIdx.x;
    if (tid < 3) part[tid] = 0.0f;
    __syncthreads();
    int p = blockIdx.x * 256 + tid;
    int row = p >> 1, f = p & 1;
    const float* tp = t_g + (size_t)row * 6 + f * 3;
    atomicAdd(&part[0], tanhf(tp[0] + fb[0]));
    atomicAdd(&part[1], tanhf(tp[1] + fb[1]));
    atomicAdd(&part[2], tanhf(tp[2] + fb[2]));
    __syncthreads();
    if (tid < 3) {
        int b = blockIdx.x >> 4;     // 16 blocks per batch
        atomicAdd(&wacc[b * 3 + tid], part[tid]);
    }
}

// ---------------------------------------------------------------------------
// Gate, strip-mined: g[r,d] = gelu(conv3_w(xs)[r,d] * v[r,d]), w = wacc/S.
// ---------------------------------------------------------------------------
__global__ void gate_k(const u16* __restrict__ xs, const float* __restrict__ v,
                       const float* __restrict__ wacc, u16* __restrict__ g) {
    const int c = blockIdx.x * 1024 + threadIdx.x * 4;
    const int r0 = blockIdx.y * STRIP;
    const int t0 = r0 & (S_ - 1);
    const int b = r0 >> 11;
    const float w0 = wacc[b * 3 + 0] * (1.0f / (float)S_);
    const float w1 = wacc[b * 3 + 1] * (1.0f / (float)S_);
    const float w2 = wacc[b * 3 + 2] * (1.0f / (float)S_);

    const u16* base = xs + (size_t)r0 * D_ + c;
    f32x4 m2, m1;
    if (t0 == 0) {
        m2 = (f32x4)(0.0f); m1 = (f32x4)(0.0f);
    } else {
        u16x4 a2 = *(const u16x4*)(base - 2 * D_);
        u16x4 a1 = *(const u16x4*)(base - D_);
        #pragma unroll
        for (int e = 0; e < 4; ++e) { m2[e] = b2f(a2[e]); m1[e] = b2f(a1[e]); }
    }

    const float* vp = v + (size_t)r0 * D_ + c;
    u16* op = g + (size_t)r0 * D_ + c;
    #pragma unroll
    for (int rr = 0; rr < STRIP; ++rr) {
        u16x4 cb = *(const u16x4*)(base + (size_t)rr * D_);
        f32x4 vv = *(const f32x4*)(vp + (size_t)rr * D_);
        f32x4 cur;
        #pragma unroll
        for (int e = 0; e < 4; ++e) cur[e] = b2f(cb[e]);
        u16x4 outv;
        #pragma unroll
        for (int e = 0; e < 4; ++e) {
            float conv = w0 * m2[e] + w1 * m1[e] + w2 * cur[e];
            outv[e] = f2b(gelu_exact(conv * vv[e]));
        }
        *(u16x4*)(op + (size_t)rr * D_) = outv;
        m2 = m1; m1 = cur;
    }
}

// ---------------------------------------------------------------------------
extern "C" void kernel_launch(void* const* d_in, const int* in_sizes, int n_in,
                              void* d_out, int out_size, void* d_ws, size_t ws_size,
                              hipStream_t stream) {
    const float* x       = (const float*)d_in[0];
    const float* short_w = (const float*)d_in[1];
    const float* short_b = (const float*)d_in[2];
    const float* proj_w  = (const float*)d_in[3];
    const float* proj_b  = (const float*)d_in[4];
    const float* filt_w  = (const float*)d_in[5];
    const float* filt_b  = (const float*)d_in[6];
    const float* out_w   = (const float*)d_in[7];
    const float* out_b   = (const float*)d_in[8];
    float* out = (float*)d_out;

    // ws: wacc | t_g | xs bf16 32MB | g bf16 32MB | wT1 8MB [| wT2 8MB]
    char* ws = (char*)d_ws;
    const size_t xs_bytes = (size_t)MROWS * D_ * 2;   // 33,554,432
    const size_t wt_bytes = (size_t)KDIM * NDIM * 2;  // 8,388,608
    float* wacc = (float*)(ws);
    float* t_g  = (float*)(ws + 1024);                // 8192*6 fp32
    u16*   xs   = (u16*)(ws + 262144);
    u16*   g    = (u16*)(ws + 262144 + xs_bytes);
    u16*   wT1  = (u16*)(ws + 262144 + 2 * xs_bytes);
    const size_t need_dual = 262144 + 2 * xs_bytes + 2 * wt_bytes;
    const bool dual = (ws_size >= need_dual);
    u16* wT2 = dual ? (u16*)(ws + 262144 + 2 * xs_bytes + wt_bytes) : wT1;

    dim3 tb(32, 8, 1);

    if (dual) {
        dim3 tg(D_ / 32, D_ / 32, 2);
        transpose_k<<<tg, tb, 0, stream>>>(proj_w, wT1, out_w, wT2, D_);
    } else {
        dim3 tg(D_ / 32, D_ / 32, 1);
        transpose_k<<<tg, tb, 0, stream>>>(proj_w, wT1, proj_w, wT1, D_);
    }

    dim3 cg(2, MROWS / STRIP, 1);   // 1024 blocks
    shortconv_k<<<cg, 256, 0, stream>>>(x, short_w, short_b, xs, wacc, t_g);

    dim3 gg(NDIM / 256, MROWS / 256, 1);     // (8, 32) = 256 blocks, 1/CU
    gemm_f8<<<gg, 512, 0, stream>>>(xs, wT1, proj_b, filt_w, t_g);

    filt_finish_k<<<64, 256, 0, stream>>>(t_g, filt_b, wacc);

    if (!dual) {
        dim3 tg(D_ / 32, D_ / 32, 1);
        transpose_k<<<tg, tb, 0, stream>>>(out_w, wT2, out_w, wT2, D_);
    }

    gate_k<<<cg, 256, 0, stream>>>(xs, x, wacc, g);

    gemm8_k<<<gg, 512, 0, stream>>>(g, wT2, out_b, out);
}